// Round 1
// baseline (685.749 us; speedup 1.0000x reference)
//
#include <hip/hip_runtime.h>
#include <stdint.h>

#define B_ 2
#define S_ 1024
#define D_ 4096
#define H_ 32
#define KVH_ 8
#define HD_ 128

typedef short short8 __attribute__((ext_vector_type(8)));
typedef float floatx4 __attribute__((ext_vector_type(4)));

__device__ __forceinline__ ushort f2bf(float f) {
  union { float f; uint32_t u; } v; v.f = f;
  return (ushort)((v.u + 0x7FFFu + ((v.u >> 16) & 1u)) >> 16);
}

__device__ __forceinline__ void gload16(const void* g, void* l) {
  __builtin_amdgcn_global_load_lds((__attribute__((address_space(1))) void*)g,
                                   (__attribute__((address_space(3))) void*)l,
                                   16, 0, 0);
}

// ---------------- f32 -> bf16 convert (8 elems/thread) ----------------
__global__ __launch_bounds__(256) void k_cvt(const float* __restrict__ in,
                                             ushort* __restrict__ out, int n8) {
  int i = blockIdx.x * 256 + threadIdx.x;
  if (i >= n8) return;
  const float4* p = (const float4*)in + (size_t)i * 2;
  float4 a = p[0], b = p[1];
  ushort o8[8] = {f2bf(a.x), f2bf(a.y), f2bf(a.z), f2bf(a.w),
                  f2bf(b.x), f2bf(b.y), f2bf(b.z), f2bf(b.w)};
  *(uint4*)(out + (size_t)i * 8) = *(uint4*)o8;
}

// ------------- f32 [R x C] -> bf16 transposed [C x R] -------------
__global__ __launch_bounds__(256) void k_tr(const float* __restrict__ in,
                                            ushort* __restrict__ out,
                                            int in_stride, int out_stride) {
  __shared__ float t[32][33];
  int n0 = blockIdx.x * 32, k0 = blockIdx.y * 32;
  int tx = threadIdx.x & 31, ty = threadIdx.x >> 5;  // ty 0..7
#pragma unroll
  for (int r = 0; r < 32; r += 8)
    t[ty + r][tx] = in[(size_t)(k0 + ty + r) * in_stride + n0 + tx];
  __syncthreads();
#pragma unroll
  for (int r = 0; r < 32; r += 8)
    out[(size_t)(n0 + ty + r) * out_stride + k0 + tx] = f2bf(t[tx][ty + r]);
}

// ------------- xa[m][0..3] = x[m,:] @ [lora_q_a | lora_v_a] -------------
__global__ __launch_bounds__(256) void k_lora(const float* __restrict__ x,
                                              const float* __restrict__ qa,
                                              const float* __restrict__ va,
                                              float* __restrict__ xa) {
  int row = blockIdx.x * 4 + (threadIdx.x >> 6);
  int lane = threadIdx.x & 63;
  const float* xr = x + (size_t)row * D_;
  float a0 = 0, a1 = 0, a2 = 0, a3 = 0;
  for (int k = lane; k < D_; k += 64) {
    float xv = xr[k];
    a0 += xv * qa[2 * k];  a1 += xv * qa[2 * k + 1];
    a2 += xv * va[2 * k];  a3 += xv * va[2 * k + 1];
  }
#pragma unroll
  for (int off = 32; off; off >>= 1) {
    a0 += __shfl_down(a0, off, 64);
    a1 += __shfl_down(a1, off, 64);
    a2 += __shfl_down(a2, off, 64);
    a3 += __shfl_down(a3, off, 64);
  }
  if (lane == 0) {
    float* o = xa + (size_t)row * 4;
    o[0] = a0; o[1] = a1; o[2] = a2; o[3] = a3;
  }
}

// ---- bf16 GEMM: C[M x N] = A[M x K] * Bt[N x K]^T (+ rank-2 LoRA epi) ----
// 128x128 tile, BK=32, 4 waves (2x2), 16x16x32 MFMA, global_load_lds staging.
__global__ __launch_bounds__(256) void k_gemm(const ushort* __restrict__ A,
                                              const ushort* __restrict__ Bt,
                                              float* __restrict__ C,
                                              int N, int K,
                                              const float* __restrict__ xa,
                                              const float* __restrict__ qb,
                                              const float* __restrict__ vb) {
  __shared__ ushort As[128 * 32];
  __shared__ ushort Bs[128 * 32];
  const int m0 = blockIdx.y * 128, n0 = blockIdx.x * 128;
  const int tid = threadIdx.x, lane = tid & 63, w = tid >> 6;
  const int wr = w >> 1, wc = w & 1;
  const int lr = lane & 15, g = lane >> 4;
  floatx4 acc[4][4] = {};
  const size_t Kz = (size_t)K;
  const ushort* Ag = A + (size_t)(m0 + w * 32 + (lane >> 2)) * Kz + (lane & 3) * 8;
  const ushort* Bg = Bt + (size_t)(n0 + w * 32 + (lane >> 2)) * Kz + (lane & 3) * 8;
  char* AsW = (char*)As + w * 2048;
  char* BsW = (char*)Bs + w * 2048;
  for (int k0 = 0; k0 < K; k0 += 32) {
    gload16(Ag + k0, AsW);
    gload16(Ag + 16 * Kz + k0, AsW + 1024);
    gload16(Bg + k0, BsW);
    gload16(Bg + 16 * Kz + k0, BsW + 1024);
    __syncthreads();
    short8 af[4], bf[4];
#pragma unroll
    for (int i = 0; i < 4; i++) {
      af[i] = *(const short8*)&As[(wr * 64 + i * 16 + lr) * 32 + g * 8];
      bf[i] = *(const short8*)&Bs[(wc * 64 + i * 16 + lr) * 32 + g * 8];
    }
#pragma unroll
    for (int i = 0; i < 4; i++)
#pragma unroll
      for (int j = 0; j < 4; j++)
        acc[i][j] = __builtin_amdgcn_mfma_f32_16x16x32_bf16(af[i], bf[j], acc[i][j], 0, 0, 0);
    __syncthreads();
  }
#pragma unroll
  for (int i = 0; i < 4; i++) {
    int m = m0 + wr * 64 + i * 16 + g * 4;
#pragma unroll
    for (int j = 0; j < 4; j++) {
      int n = n0 + wc * 64 + j * 16 + lr;
#pragma unroll
      for (int r = 0; r < 4; r++) {
        float c = acc[i][j][r];
        if (xa) {
          if (n < 4096)
            c += xa[(size_t)(m + r) * 4 + 0] * qb[n] +
                 xa[(size_t)(m + r) * 4 + 1] * qb[4096 + n];
          else if (n >= 5120)
            c += xa[(size_t)(m + r) * 4 + 2] * vb[n - 5120] +
                 xa[(size_t)(m + r) * 4 + 3] * vb[1024 + n - 5120];
        }
        C[(size_t)(m + r) * N + n] = c;
      }
    }
  }
}

// ---- RoPE (interleaved pairs) + repack to (b,h,s,d) bf16 for Q and K ----
__global__ __launch_bounds__(256) void k_rope(const float* __restrict__ xqkv,
                                              const float* __restrict__ fcos,
                                              const float* __restrict__ fsin,
                                              ushort* __restrict__ Qb,
                                              ushort* __restrict__ Kb) {
  const int s = blockIdx.x, b = blockIdx.y;
  const float* row = xqkv + (size_t)(b * S_ + s) * 6144;
#pragma unroll
  for (int it = 0; it < 8; it++) {  // Q: 32 heads * 64 pairs
    int p2 = it * 256 + threadIdx.x;
    int h = p2 >> 6, p = p2 & 63;
    float2 ab = *(const float2*)(row + h * 128 + 2 * p);
    float c = fcos[s * 64 + p], sn = fsin[s * 64 + p];
    uint32_t pk = (uint32_t)f2bf(ab.x * c - ab.y * sn) |
                  ((uint32_t)f2bf(ab.x * sn + ab.y * c) << 16);
    *(uint32_t*)(Qb + ((size_t)(b * H_ + h) * S_ + s) * HD_ + 2 * p) = pk;
  }
#pragma unroll
  for (int it = 0; it < 2; it++) {  // K: 8 heads * 64 pairs
    int p2 = it * 256 + threadIdx.x;
    int h = p2 >> 6, p = p2 & 63;
    float2 ab = *(const float2*)(row + 4096 + h * 128 + 2 * p);
    float c = fcos[s * 64 + p], sn = fsin[s * 64 + p];
    uint32_t pk = (uint32_t)f2bf(ab.x * c - ab.y * sn) |
                  ((uint32_t)f2bf(ab.x * sn + ab.y * c) << 16);
    *(uint32_t*)(Kb + ((size_t)(b * KVH_ + h) * S_ + s) * HD_ + 2 * p) = pk;
  }
}

// ---- flash attention: swapped QK^T (St = K*Q^T), online softmax, PV ----
// grid (S/64, H, B), 4 waves * 16 q-rows. Q/K from global (b,h,s,d) bf16,
// V from global transposed (b,kvh,d,s) bf16. P routed via swizzled LDS.
__global__ __launch_bounds__(256) void k_flash(const ushort* __restrict__ Qb,
                                               const ushort* __restrict__ Kb,
                                               const ushort* __restrict__ Vt,
                                               ushort* __restrict__ attn) {
  __shared__ ushort Plds[4096];  // 4 waves * 16x64 bf16 (XOR-swizzled)
  const int qblk = blockIdx.x, h = blockIdx.y, b = blockIdx.z;
  const int kvh = h >> 2;
  const int tid = threadIdx.x, w = tid >> 6, lane = tid & 63;
  const int lr = lane & 15, g = lane >> 4;
  const int qr0 = qblk * 64 + w * 16;
  const ushort* Qrow = Qb + ((size_t)(b * H_ + h) * S_ + qr0 + lr) * HD_;
  short8 qf[4];
#pragma unroll
  for (int ks = 0; ks < 4; ks++) qf[ks] = *(const short8*)(Qrow + ks * 32 + g * 8);
  const ushort* Kbase = Kb + (size_t)(b * KVH_ + kvh) * S_ * HD_;
  const ushort* Vbase = Vt + (size_t)(b * KVH_ + kvh) * HD_ * S_;
  char* Pw = (char*)Plds + w * 2048;
  const int q7 = lr & 7;
  float m_run = -1e30f, l_run = 0.f;
  floatx4 o[8] = {};
  const int nt = qblk + 1;
  for (int t = 0; t < nt; t++) {
    floatx4 s4[4] = {};
#pragma unroll
    for (int mf = 0; mf < 4; mf++) {
      const ushort* Krow = Kbase + (size_t)(t * 64 + mf * 16 + lr) * HD_;
#pragma unroll
      for (int ks = 0; ks < 4; ks++) {
        short8 kf = *(const short8*)(Krow + ks * 32 + g * 8);
        s4[mf] = __builtin_amdgcn_mfma_f32_16x16x32_bf16(kf, qf[ks], s4[mf], 0, 0, 0);
      }
    }
    const float scale = 0.088388347648318447f;  // 1/sqrt(128)
    float tm = -1e30f;
    if (t == qblk) {
#pragma unroll
      for (int mf = 0; mf < 4; mf++)
#pragma unroll
        for (int r = 0; r < 4; r++) {
          int kv = t * 64 + mf * 16 + g * 4 + r;
          float v = (kv > qr0 + lr) ? -1e30f : s4[mf][r] * scale;
          s4[mf][r] = v;
          tm = fmaxf(tm, v);
        }
    } else {
#pragma unroll
      for (int mf = 0; mf < 4; mf++)
#pragma unroll
        for (int r = 0; r < 4; r++) {
          float v = s4[mf][r] * scale;
          s4[mf][r] = v;
          tm = fmaxf(tm, v);
        }
    }
    tm = fmaxf(tm, __shfl_xor(tm, 16, 64));
    tm = fmaxf(tm, __shfl_xor(tm, 32, 64));
    float m_new = fmaxf(m_run, tm);
    float corr = __expf(m_run - m_new);
    float rs = 0.f;
#pragma unroll
    for (int mf = 0; mf < 4; mf++)
#pragma unroll
      for (int r = 0; r < 4; r++) {
        float p = __expf(s4[mf][r] - m_new);
        s4[mf][r] = p;
        rs += p;
      }
    rs += __shfl_xor(rs, 16, 64);
    rs += __shfl_xor(rs, 32, 64);
    l_run = l_run * corr + rs;
    m_run = m_new;
#pragma unroll
    for (int r = 0; r < 4; r++) {
      float cr = __shfl(corr, g * 4 + r, 64);
#pragma unroll
      for (int nf = 0; nf < 8; nf++) o[nf][r] *= cr;
    }
    // P^T -> LDS (bf16, per-wave buffer, XOR-swizzled rows of 128B)
#pragma unroll
    for (int mf = 0; mf < 4; mf++) {
      uint2 pv;
      pv.x = (uint32_t)f2bf(s4[mf][0]) | ((uint32_t)f2bf(s4[mf][1]) << 16);
      pv.y = (uint32_t)f2bf(s4[mf][2]) | ((uint32_t)f2bf(s4[mf][3]) << 16);
      *(uint2*)(Pw + lr * 128 + ((mf * 32 + g * 8) ^ (q7 << 4))) = pv;
    }
    // PV: O += P * V
#pragma unroll
    for (int ks2 = 0; ks2 < 2; ks2++) {
      short8 pa = *(const short8*)(Pw + lr * 128 + ((ks2 * 64 + g * 16) ^ (q7 << 4)));
      const ushort* Vc = Vbase + (size_t)lr * S_ + t * 64 + ks2 * 32 + g * 8;
#pragma unroll
      for (int nf = 0; nf < 8; nf++) {
        short8 vf = *(const short8*)(Vc + (size_t)nf * 16 * S_);
        o[nf] = __builtin_amdgcn_mfma_f32_16x16x32_bf16(pa, vf, o[nf], 0, 0, 0);
      }
    }
  }
  float linv = 1.0f / l_run;
  ushort* outp = attn + ((size_t)(b * S_) + qr0) * 4096 + h * 128;
#pragma unroll
  for (int r = 0; r < 4; r++) {
    float li = __shfl(linv, g * 4 + r, 64);
    ushort* orow = outp + (size_t)(g * 4 + r) * 4096;
#pragma unroll
    for (int nf = 0; nf < 8; nf++)
      orow[nf * 16 + lr] = f2bf(o[nf][r] * li);
  }
}

extern "C" void kernel_launch(void* const* d_in, const int* in_sizes, int n_in,
                              void* d_out, int out_size, void* d_ws, size_t ws_size,
                              hipStream_t stream) {
  (void)in_sizes; (void)n_in; (void)out_size; (void)ws_size;
  const float* x    = (const float*)d_in[0];
  const float* wq   = (const float*)d_in[1];
  const float* wk   = (const float*)d_in[2];
  const float* wv   = (const float*)d_in[3];
  const float* wo   = (const float*)d_in[4];
  const float* lqa  = (const float*)d_in[5];
  const float* lqb  = (const float*)d_in[6];
  const float* lva  = (const float*)d_in[7];
  const float* lvb  = (const float*)d_in[8];
  const float* fcos = (const float*)d_in[9];
  const float* fsin = (const float*)d_in[10];
  // d_in[11] = mask (replicated by causal logic), d_in[12] = start_pos (0)

  char* ws = (char*)d_ws;
  ushort* xb   = (ushort*)(ws + 0);           // x bf16              16,777,216 B
  ushort* wT   = (ushort*)(ws + 16777216);    // [wq|wk|wv]^T bf16   50,331,648 B
  ushort* woT  = (ushort*)(ws + 67108864);    // wo^T bf16           33,554,432 B
  float*  xqkv = (float*) (ws + 100663296);   // 2048x6144 f32       50,331,648 B
  ushort* Qb   = (ushort*)(ws + 150994944);   // (b,h,s,d) bf16      16,777,216 B
  ushort* Kb   = (ushort*)(ws + 167772160);   // (b,kvh,s,d) bf16     4,194,304 B
  ushort* Vt   = (ushort*)(ws + 171966464);   // (b,kvh,d,s) bf16     4,194,304 B
  ushort* attn = (ushort*)(ws + 176160768);   // 2048x4096 bf16      16,777,216 B
  float*  xa   = (float*) (ws + 192937984);   // 2048x4 f32              32,768 B

  // 1) conversions / transposes
  k_cvt<<<4096, 256, 0, stream>>>(x, xb, 1048576);
  k_tr<<<dim3(128, 128), 256, 0, stream>>>(wq, wT, 4096, 4096);
  k_tr<<<dim3(32, 128), 256, 0, stream>>>(wk, wT + (size_t)4096 * 4096, 1024, 4096);
  k_tr<<<dim3(32, 128), 256, 0, stream>>>(wv, wT + (size_t)5120 * 4096, 1024, 4096);
  k_tr<<<dim3(128, 128), 256, 0, stream>>>(wo, woT, 4096, 4096);
  // 2) LoRA rank-2 projections
  k_lora<<<512, 256, 0, stream>>>(x, lqa, lva, xa);
  // 3) fused QKV GEMM + LoRA epilogue -> xqkv f32
  k_gemm<<<dim3(48, 16), 256, 0, stream>>>(xb, wT, xqkv, 6144, 4096, xa, lqb, lvb);
  // 4) RoPE + repack Q,K ; V transpose (per batch)
  k_rope<<<dim3(1024, 2), 256, 0, stream>>>(xqkv, fcos, fsin, Qb, Kb);
  k_tr<<<dim3(32, 32), 256, 0, stream>>>(xqkv + 5120, Vt, 6144, 1024);
  k_tr<<<dim3(32, 32), 256, 0, stream>>>(xqkv + (size_t)1024 * 6144 + 5120, Vt + 1048576, 6144, 1024);
  // 5) flash attention -> attn bf16 (2048 x 4096)
  k_flash<<<dim3(16, 32, 2), 256, 0, stream>>>(Qb, Kb, Vt, attn);
  // 6) output projection -> d_out f32
  k_gemm<<<dim3(32, 16), 256, 0, stream>>>(attn, woT, (float*)d_out, 4096, 4096,
                                           nullptr, nullptr, nullptr);
}

// Round 2
// 410.639 us; speedup vs baseline: 1.6700x; 1.6700x over previous
//
#include <hip/hip_runtime.h>
#include <stdint.h>

#define B_ 2
#define S_ 1024
#define D_ 4096
#define H_ 32
#define KVH_ 8
#define HD_ 128

typedef short short8 __attribute__((ext_vector_type(8)));
typedef float floatx4 __attribute__((ext_vector_type(4)));

__device__ __forceinline__ ushort f2bf(float f) {
  union { float f; uint32_t u; } v; v.f = f;
  return (ushort)((v.u + 0x7FFFu + ((v.u >> 16) & 1u)) >> 16);
}

__device__ __forceinline__ void gload16(const void* g, void* l) {
  __builtin_amdgcn_global_load_lds((__attribute__((address_space(1))) void*)g,
                                   (__attribute__((address_space(3))) void*)l,
                                   16, 0, 0);
}

// ---------------- f32 -> bf16 convert (8 elems/thread) ----------------
__global__ __launch_bounds__(256) void k_cvt(const float* __restrict__ in,
                                             ushort* __restrict__ out, int n8) {
  int i = blockIdx.x * 256 + threadIdx.x;
  if (i >= n8) return;
  const float4* p = (const float4*)in + (size_t)i * 2;
  float4 a = p[0], b = p[1];
  ushort o8[8] = {f2bf(a.x), f2bf(a.y), f2bf(a.z), f2bf(a.w),
                  f2bf(b.x), f2bf(b.y), f2bf(b.z), f2bf(b.w)};
  *(uint4*)(out + (size_t)i * 8) = *(uint4*)o8;
}

// ------------- f32 [R x C] -> bf16 transposed [C x R] -------------
__global__ __launch_bounds__(256) void k_tr(const float* __restrict__ in,
                                            ushort* __restrict__ out,
                                            int in_stride, int out_stride) {
  __shared__ float t[32][33];
  int n0 = blockIdx.x * 32, k0 = blockIdx.y * 32;
  int tx = threadIdx.x & 31, ty = threadIdx.x >> 5;  // ty 0..7
#pragma unroll
  for (int r = 0; r < 32; r += 8)
    t[ty + r][tx] = in[(size_t)(k0 + ty + r) * in_stride + n0 + tx];
  __syncthreads();
#pragma unroll
  for (int r = 0; r < 32; r += 8)
    out[(size_t)(n0 + ty + r) * out_stride + k0 + tx] = f2bf(t[tx][ty + r]);
}

// ------------- xa[m][0..3] = x[m,:] @ [lora_q_a | lora_v_a] -------------
__global__ __launch_bounds__(256) void k_lora(const float* __restrict__ x,
                                              const float* __restrict__ qa,
                                              const float* __restrict__ va,
                                              float* __restrict__ xa) {
  int row = blockIdx.x * 4 + (threadIdx.x >> 6);
  int lane = threadIdx.x & 63;
  const float* xr = x + (size_t)row * D_;
  float a0 = 0, a1 = 0, a2 = 0, a3 = 0;
  for (int k = lane; k < D_; k += 64) {
    float xv = xr[k];
    a0 += xv * qa[2 * k];  a1 += xv * qa[2 * k + 1];
    a2 += xv * va[2 * k];  a3 += xv * va[2 * k + 1];
  }
#pragma unroll
  for (int off = 32; off; off >>= 1) {
    a0 += __shfl_down(a0, off, 64);
    a1 += __shfl_down(a1, off, 64);
    a2 += __shfl_down(a2, off, 64);
    a3 += __shfl_down(a3, off, 64);
  }
  if (lane == 0) {
    float* o = xa + (size_t)row * 4;
    o[0] = a0; o[1] = a1; o[2] = a2; o[3] = a3;
  }
}

// ==================== 256x256 8-phase bf16 GEMM ====================
// C[M x N] = A[M x K] * Bt[N x K]^T (+ rank-2 LoRA epilogue).
// 8 waves (2Mx4N), BK=64, 128KB LDS dbuf, per-phase half-tile staging,
// counted vmcnt(4), XOR swizzle via pre-swizzled global source.
#define STAGE_A(HALF, KT, DBUF) do {                                         \
    const ushort* gp_ = A + (size_t)(m0 + (HALF) * 128 + w * 16 + srow) * Kz \
                          + (KT) * 64 + scol;                                \
    char* lp_ = lds + (DBUF) * 65536 + (HALF) * 16384 + w * 2048;            \
    gload16(gp_, lp_);                                                       \
    gload16(gp_ + 8 * Kz, lp_ + 1024);                                       \
  } while (0)

#define STAGE_B(HALF, KT, DBUF) do {                                         \
    const ushort* gp_ = Bt + (size_t)(n0 + (HALF) * 128 + w * 16 + srow) * Kz\
                          + (KT) * 64 + scol;                                \
    char* lp_ = lds + (DBUF) * 65536 + 32768 + (HALF) * 16384 + w * 2048;    \
    gload16(gp_, lp_);                                                       \
    gload16(gp_ + 8 * Kz, lp_ + 1024);                                       \
  } while (0)

#define LOAD_AF(QA, CUR) do {                                                \
    const char* ab_ = lds + (CUR) * 65536 + (QA) * 16384 + (wr * 64 + lr) * 128; \
    _Pragma("unroll") for (int fr = 0; fr < 4; fr++)                         \
    _Pragma("unroll") for (int ks = 0; ks < 2; ks++)                         \
      af[fr][ks] = *(const short8*)(ab_ + fr * 2048 + (((ks * 4 + g) * 16) ^ swz)); \
  } while (0)

#define LOAD_BF(QB, CUR, BF) do {                                            \
    const char* bb_ = lds + (CUR) * 65536 + 32768 + (QB) * 16384 + (wc * 32 + lr) * 128; \
    _Pragma("unroll") for (int fc = 0; fc < 2; fc++)                         \
    _Pragma("unroll") for (int ks = 0; ks < 2; ks++)                         \
      BF[fc][ks] = *(const short8*)(bb_ + fc * 2048 + (((ks * 4 + g) * 16) ^ swz)); \
  } while (0)

#define MFMA16(QA, QB, BF) do {                                              \
    __builtin_amdgcn_s_setprio(1);                                           \
    _Pragma("unroll") for (int fr = 0; fr < 4; fr++)                         \
    _Pragma("unroll") for (int fc = 0; fc < 2; fc++)                         \
    _Pragma("unroll") for (int ks = 0; ks < 2; ks++)                         \
      acc[(QA) * 4 + fr][(QB) * 2 + fc] = __builtin_amdgcn_mfma_f32_16x16x32_bf16( \
          af[fr][ks], BF[fc][ks], acc[(QA) * 4 + fr][(QB) * 2 + fc], 0, 0, 0);     \
    __builtin_amdgcn_s_setprio(0);                                           \
  } while (0)

#define GBAR __builtin_amdgcn_s_barrier()
#define LGKM0 asm volatile("s_waitcnt lgkmcnt(0)" ::: "memory")

__global__ __launch_bounds__(512, 2) void k_gemm8(const ushort* __restrict__ A,
                                                  const ushort* __restrict__ Bt,
                                                  float* __restrict__ C,
                                                  int N, int K,
                                                  const float* __restrict__ xa,
                                                  const float* __restrict__ qb,
                                                  const float* __restrict__ vb) {
  __shared__ char lds[131072];
  // bijective XCD swizzle (nwg % 8 == 0 for both launches)
  const int nbx = gridDim.x;
  const int nwg = nbx * gridDim.y;
  const int flat = blockIdx.y * nbx + blockIdx.x;
  const int swz_id = (flat & 7) * (nwg >> 3) + (flat >> 3);
  const int m0 = (swz_id / nbx) * 256, n0 = (swz_id % nbx) * 256;
  const int tid = threadIdx.x, lane = tid & 63, w = tid >> 6;
  const int wr = w >> 2, wc = w & 3;  // 2 x 4 waves
  const int lr = lane & 15, g = lane >> 4;
  const int swz = (lr & 7) * 16;
  const size_t Kz = (size_t)K;
  const int NK = K >> 6;
  const int srow = lane >> 3;                           // 0..7
  const int scol = ((lane & 7) ^ (srow & 7)) * 8;       // pre-swizzled source col

  floatx4 acc[8][4] = {};
  short8 af[4][2], bf0[2][2], bf1[2][2];

  // prologue: K-tile 0 fully + A halves of K-tile 1
  STAGE_A(0, 0, 0); STAGE_B(0, 0, 0); STAGE_A(1, 0, 0); STAGE_B(1, 0, 0);
  STAGE_A(0, 1, 1); STAGE_A(1, 1, 1);
  asm volatile("s_waitcnt vmcnt(4)" ::: "memory");
  GBAR;

  for (int k = 0; k < NK; ++k) {
    const int cur = k & 1, nxt = cur ^ 1;
    // P0: quadrant (0,0)
    LOAD_AF(0, cur);
    LOAD_BF(0, cur, bf0);
    if (k + 1 < NK) STAGE_B(0, k + 1, nxt);
    GBAR; LGKM0; MFMA16(0, 0, bf0); GBAR;
    // P1: quadrant (0,1)
    LOAD_BF(1, cur, bf1);
    if (k + 1 < NK) STAGE_B(1, k + 1, nxt);
    GBAR; LGKM0; MFMA16(0, 1, bf1); GBAR;
    // P2: quadrant (1,1)
    LOAD_AF(1, cur);
    if (k + 2 < NK) STAGE_A(0, k + 2, cur);
    GBAR; LGKM0; MFMA16(1, 1, bf1); GBAR;
    // P3: quadrant (1,0)
    if (k + 2 < NK) STAGE_A(1, k + 2, cur);
    if (k < NK - 2) asm volatile("s_waitcnt vmcnt(4)" ::: "memory");
    else            asm volatile("s_waitcnt vmcnt(0)" ::: "memory");
    GBAR; LGKM0; MFMA16(1, 0, bf0); GBAR;
  }

  // epilogue: C write + optional rank-2 LoRA
#pragma unroll
  for (int qa = 0; qa < 2; qa++)
#pragma unroll
    for (int fr = 0; fr < 4; fr++) {
      const int mb = m0 + qa * 128 + wr * 64 + fr * 16 + g * 4;
#pragma unroll
      for (int qb_ = 0; qb_ < 2; qb_++)
#pragma unroll
        for (int fc = 0; fc < 2; fc++) {
          const int n = n0 + qb_ * 128 + wc * 32 + fc * 16 + lr;
#pragma unroll
          for (int r = 0; r < 4; r++) {
            const int m = mb + r;
            float c = acc[qa * 4 + fr][qb_ * 2 + fc][r];
            if (xa) {
              if (n < 4096)
                c += xa[(size_t)m * 4 + 0] * qb[n] +
                     xa[(size_t)m * 4 + 1] * qb[4096 + n];
              else if (n >= 5120)
                c += xa[(size_t)m * 4 + 2] * vb[n - 5120] +
                     xa[(size_t)m * 4 + 3] * vb[1024 + n - 5120];
            }
            C[(size_t)m * N + n] = c;
          }
        }
    }
}

// ---- RoPE (interleaved pairs) + repack to (b,h,s,d) bf16 for Q and K ----
__global__ __launch_bounds__(256) void k_rope(const float* __restrict__ xqkv,
                                              const float* __restrict__ fcos,
                                              const float* __restrict__ fsin,
                                              ushort* __restrict__ Qb,
                                              ushort* __restrict__ Kb) {
  const int s = blockIdx.x, b = blockIdx.y;
  const float* row = xqkv + (size_t)(b * S_ + s) * 6144;
#pragma unroll
  for (int it = 0; it < 8; it++) {  // Q: 32 heads * 64 pairs
    int p2 = it * 256 + threadIdx.x;
    int h = p2 >> 6, p = p2 & 63;
    float2 ab = *(const float2*)(row + h * 128 + 2 * p);
    float c = fcos[s * 64 + p], sn = fsin[s * 64 + p];
    uint32_t pk = (uint32_t)f2bf(ab.x * c - ab.y * sn) |
                  ((uint32_t)f2bf(ab.x * sn + ab.y * c) << 16);
    *(uint32_t*)(Qb + ((size_t)(b * H_ + h) * S_ + s) * HD_ + 2 * p) = pk;
  }
#pragma unroll
  for (int it = 0; it < 2; it++) {  // K: 8 heads * 64 pairs
    int p2 = it * 256 + threadIdx.x;
    int h = p2 >> 6, p = p2 & 63;
    float2 ab = *(const float2*)(row + 4096 + h * 128 + 2 * p);
    float c = fcos[s * 64 + p], sn = fsin[s * 64 + p];
    uint32_t pk = (uint32_t)f2bf(ab.x * c - ab.y * sn) |
                  ((uint32_t)f2bf(ab.x * sn + ab.y * c) << 16);
    *(uint32_t*)(Kb + ((size_t)(b * KVH_ + h) * S_ + s) * HD_ + 2 * p) = pk;
  }
}

// ==================== flash attention, LDS-staged K/V ====================
// grid (S/64, H, B), 4 waves * 16 q-rows. K tile [64s][128d] and V tile
// [128d][64s] double-buffered in LDS via pre-swizzled global_load_lds;
// 2-phase pipeline (stage t+1, compute t, vmcnt(0)+barrier).
#define FSTAGE(T, DB) do {                                                   \
    _Pragma("unroll") for (int i_ = 0; i_ < 4; i_++) {                       \
      gload16(Kg + (size_t)((T) * 64 + i_ * 16 + k_srow) * HD_ + k_scol,     \
              fls + (DB) * 16384 + i_ * 4096 + w * 1024);                    \
      gload16(Vg + (size_t)(i_ * 32 + v_srow) * S_ + (T) * 64 + v_scol,      \
              fls + 32768 + (DB) * 16384 + i_ * 4096 + w * 1024);            \
    }                                                                        \
  } while (0)

__global__ __launch_bounds__(256, 2) void k_flash(const ushort* __restrict__ Qb,
                                                  const ushort* __restrict__ Kb,
                                                  const ushort* __restrict__ Vt,
                                                  ushort* __restrict__ attn) {
  __shared__ char fls[73728];  // K dbuf 32KB | V dbuf 32KB | P 8KB
  const int qblk = (gridDim.x - 1) - blockIdx.x;  // heavy blocks first
  const int h = blockIdx.y, b = blockIdx.z;
  const int kvh = h >> 2;
  const int tid = threadIdx.x, w = tid >> 6, lane = tid & 63;
  const int lr = lane & 15, g = lane >> 4;
  const int swz = (lr & 7) * 16;
  const int qr0 = qblk * 64 + w * 16;
  const ushort* Qrow = Qb + ((size_t)(b * H_ + h) * S_ + qr0 + lr) * HD_;
  short8 qf[4];
#pragma unroll
  for (int ks = 0; ks < 4; ks++) qf[ks] = *(const short8*)(Qrow + ks * 32 + g * 8);
  const ushort* Kg = Kb + (size_t)(b * KVH_ + kvh) * S_ * HD_;
  const ushort* Vg = Vt + (size_t)(b * KVH_ + kvh) * HD_ * S_;
  char* Pw = fls + 65536 + w * 2048;
  const int q7 = lr & 7;
  const int k_srow = tid >> 4;                          // 0..15
  const int k_scol = ((tid & 15) ^ (k_srow & 7)) * 8;   // pre-swizzled
  const int v_srow = tid >> 3;                          // 0..31
  const int v_scol = ((tid & 7) ^ (v_srow & 7)) * 8;

  float m_run = -1e30f, l_run = 0.f;
  floatx4 o[8] = {};
  const int nt = qblk + 1;

  FSTAGE(0, 0);
  asm volatile("s_waitcnt vmcnt(0)" ::: "memory");
  __builtin_amdgcn_s_barrier();

  for (int t = 0; t < nt; t++) {
    const int cur = t & 1;
    if (t + 1 < nt) FSTAGE(t + 1, cur ^ 1);
    const char* Kl = fls + cur * 16384;
    const char* Vl = fls + 32768 + cur * 16384;
    floatx4 s4[4] = {};
    __builtin_amdgcn_s_setprio(1);
#pragma unroll
    for (int mf = 0; mf < 4; mf++) {
      const char* Krow = Kl + (mf * 16 + lr) * 256;
#pragma unroll
      for (int ks = 0; ks < 4; ks++) {
        short8 kf = *(const short8*)(Krow + (((ks * 4 + g) * 16) ^ swz));
        s4[mf] = __builtin_amdgcn_mfma_f32_16x16x32_bf16(kf, qf[ks], s4[mf], 0, 0, 0);
      }
    }
    __builtin_amdgcn_s_setprio(0);
    const float scale = 0.088388347648318447f;  // 1/sqrt(128)
    float tm = -1e30f;
    if (t == nt - 1) {
#pragma unroll
      for (int mf = 0; mf < 4; mf++)
#pragma unroll
        for (int r = 0; r < 4; r++) {
          int kv = t * 64 + mf * 16 + g * 4 + r;
          float v = (kv > qr0 + lr) ? -1e30f : s4[mf][r] * scale;
          s4[mf][r] = v;
          tm = fmaxf(tm, v);
        }
    } else {
#pragma unroll
      for (int mf = 0; mf < 4; mf++)
#pragma unroll
        for (int r = 0; r < 4; r++) {
          float v = s4[mf][r] * scale;
          s4[mf][r] = v;
          tm = fmaxf(tm, v);
        }
    }
    tm = fmaxf(tm, __shfl_xor(tm, 16, 64));
    tm = fmaxf(tm, __shfl_xor(tm, 32, 64));
    float m_new = fmaxf(m_run, tm);
    float corr = __expf(m_run - m_new);
    float rs = 0.f;
#pragma unroll
    for (int mf = 0; mf < 4; mf++)
#pragma unroll
      for (int r = 0; r < 4; r++) {
        float p = __expf(s4[mf][r] - m_new);
        s4[mf][r] = p;
        rs += p;
      }
    rs += __shfl_xor(rs, 16, 64);
    rs += __shfl_xor(rs, 32, 64);
    l_run = l_run * corr + rs;
    m_run = m_new;
#pragma unroll
    for (int r = 0; r < 4; r++) {
      float cr = __shfl(corr, g * 4 + r, 64);
#pragma unroll
      for (int nf = 0; nf < 8; nf++) o[nf][r] *= cr;
    }
    // P^T -> LDS (per-wave buffer, XOR-swizzled)
#pragma unroll
    for (int mf = 0; mf < 4; mf++) {
      uint2 pv;
      pv.x = (uint32_t)f2bf(s4[mf][0]) | ((uint32_t)f2bf(s4[mf][1]) << 16);
      pv.y = (uint32_t)f2bf(s4[mf][2]) | ((uint32_t)f2bf(s4[mf][3]) << 16);
      *(uint2*)(Pw + lr * 128 + ((mf * 32 + g * 8) ^ (q7 << 4))) = pv;
    }
    // PV: O += P * V (V fragments from LDS, conflict-free)
    __builtin_amdgcn_s_setprio(1);
#pragma unroll
    for (int ks2 = 0; ks2 < 2; ks2++) {
      short8 pa = *(const short8*)(Pw + lr * 128 + ((ks2 * 64 + g * 16) ^ (q7 << 4)));
#pragma unroll
      for (int nf = 0; nf < 8; nf++) {
        short8 vf = *(const short8*)(Vl + (nf * 16 + lr) * 128 + (((ks2 * 4 + g) * 16) ^ swz));
        o[nf] = __builtin_amdgcn_mfma_f32_16x16x32_bf16(pa, vf, o[nf], 0, 0, 0);
      }
    }
    __builtin_amdgcn_s_setprio(0);
    asm volatile("s_waitcnt vmcnt(0)" ::: "memory");
    __builtin_amdgcn_s_barrier();
  }
  float linv = 1.0f / l_run;
  ushort* outp = attn + ((size_t)(b * S_) + qr0) * 4096 + h * 128;
#pragma unroll
  for (int r = 0; r < 4; r++) {
    float li = __shfl(linv, g * 4 + r, 64);
    ushort* orow = outp + (size_t)(g * 4 + r) * 4096;
#pragma unroll
    for (int nf = 0; nf < 8; nf++)
      orow[nf * 16 + lr] = f2bf(o[nf][r] * li);
  }
}

extern "C" void kernel_launch(void* const* d_in, const int* in_sizes, int n_in,
                              void* d_out, int out_size, void* d_ws, size_t ws_size,
                              hipStream_t stream) {
  (void)in_sizes; (void)n_in; (void)out_size; (void)ws_size;
  const float* x    = (const float*)d_in[0];
  const float* wq   = (const float*)d_in[1];
  const float* wk   = (const float*)d_in[2];
  const float* wv   = (const float*)d_in[3];
  const float* wo   = (const float*)d_in[4];
  const float* lqa  = (const float*)d_in[5];
  const float* lqb  = (const float*)d_in[6];
  const float* lva  = (const float*)d_in[7];
  const float* lvb  = (const float*)d_in[8];
  const float* fcos = (const float*)d_in[9];
  const float* fsin = (const float*)d_in[10];

  char* ws = (char*)d_ws;
  ushort* xb   = (ushort*)(ws + 0);           // x bf16              16,777,216 B
  ushort* wT   = (ushort*)(ws + 16777216);    // [wq|wk|wv]^T bf16   50,331,648 B
  ushort* woT  = (ushort*)(ws + 67108864);    // wo^T bf16           33,554,432 B
  float*  xqkv = (float*) (ws + 100663296);   // 2048x6144 f32       50,331,648 B
  ushort* Qb   = (ushort*)(ws + 150994944);   // (b,h,s,d) bf16      16,777,216 B
  ushort* Kb   = (ushort*)(ws + 167772160);   // (b,kvh,s,d) bf16     4,194,304 B
  ushort* Vt   = (ushort*)(ws + 171966464);   // (b,kvh,d,s) bf16     4,194,304 B
  ushort* attn = (ushort*)(ws + 176160768);   // 2048x4096 bf16      16,777,216 B
  float*  xa   = (float*) (ws + 192937984);   // 2048x4 f32              32,768 B

  // 1) conversions / transposes
  k_cvt<<<4096, 256, 0, stream>>>(x, xb, 1048576);
  k_tr<<<dim3(128, 128), 256, 0, stream>>>(wq, wT, 4096, 4096);
  k_tr<<<dim3(32, 128), 256, 0, stream>>>(wk, wT + (size_t)4096 * 4096, 1024, 4096);
  k_tr<<<dim3(32, 128), 256, 0, stream>>>(wv, wT + (size_t)5120 * 4096, 1024, 4096);
  k_tr<<<dim3(128, 128), 256, 0, stream>>>(wo, woT, 4096, 4096);
  // 2) LoRA rank-2 projections
  k_lora<<<512, 256, 0, stream>>>(x, lqa, lva, xa);
  // 3) fused QKV GEMM + LoRA epilogue -> xqkv f32 (grid 24x8 = 192 wg)
  k_gemm8<<<dim3(24, 8), 512, 0, stream>>>(xb, wT, xqkv, 6144, 4096, xa, lqb, lvb);
  // 4) RoPE + repack Q,K ; V transpose (per batch)
  k_rope<<<dim3(1024, 2), 256, 0, stream>>>(xqkv, fcos, fsin, Qb, Kb);
  k_tr<<<dim3(32, 32), 256, 0, stream>>>(xqkv + 5120, Vt, 6144, 1024);
  k_tr<<<dim3(32, 32), 256, 0, stream>>>(xqkv + (size_t)1024 * 6144 + 5120, Vt + 1048576, 6144, 1024);
  // 5) flash attention -> attn bf16 (2048 x 4096)
  k_flash<<<dim3(16, 32, 2), 256, 0, stream>>>(Qb, Kb, Vt, attn);
  // 6) output projection -> d_out f32 (grid 16x8 = 128 wg)
  k_gemm8<<<dim3(16, 8), 512, 0, stream>>>(attn, woT, (float*)d_out, 4096, 4096,
                                           nullptr, nullptr, nullptr);
}

// Round 3
// 383.808 us; speedup vs baseline: 1.7867x; 1.0699x over previous
//
#include <hip/hip_runtime.h>
#include <stdint.h>

#define B_ 2
#define S_ 1024
#define D_ 4096
#define H_ 32
#define KVH_ 8
#define HD_ 128

typedef short short8 __attribute__((ext_vector_type(8)));
typedef float floatx4 __attribute__((ext_vector_type(4)));

__device__ __forceinline__ ushort f2bf(float f) {
  union { float f; uint32_t u; } v; v.f = f;
  return (ushort)((v.u + 0x7FFFu + ((v.u >> 16) & 1u)) >> 16);
}

__device__ __forceinline__ void gload16(const void* g, void* l) {
  __builtin_amdgcn_global_load_lds((__attribute__((address_space(1))) void*)g,
                                   (__attribute__((address_space(3))) void*)l,
                                   16, 0, 0);
}

// ---------------- f32 -> bf16 convert (8 elems/thread) ----------------
__global__ __launch_bounds__(256) void k_cvt(const float* __restrict__ in,
                                             ushort* __restrict__ out, int n8) {
  int i = blockIdx.x * 256 + threadIdx.x;
  if (i >= n8) return;
  const float4* p = (const float4*)in + (size_t)i * 2;
  float4 a = p[0], b = p[1];
  ushort o8[8] = {f2bf(a.x), f2bf(a.y), f2bf(a.z), f2bf(a.w),
                  f2bf(b.x), f2bf(b.y), f2bf(b.z), f2bf(b.w)};
  *(uint4*)(out + (size_t)i * 8) = *(uint4*)o8;
}

// ------------- f32 [R x C] -> bf16 transposed [C x R] -------------
__global__ __launch_bounds__(256) void k_tr(const float* __restrict__ in,
                                            ushort* __restrict__ out,
                                            int in_stride, int out_stride) {
  __shared__ float t[32][33];
  int n0 = blockIdx.x * 32, k0 = blockIdx.y * 32;
  int tx = threadIdx.x & 31, ty = threadIdx.x >> 5;  // ty 0..7
#pragma unroll
  for (int r = 0; r < 32; r += 8)
    t[ty + r][tx] = in[(size_t)(k0 + ty + r) * in_stride + n0 + tx];
  __syncthreads();
#pragma unroll
  for (int r = 0; r < 32; r += 8)
    out[(size_t)(n0 + ty + r) * out_stride + k0 + tx] = f2bf(t[tx][ty + r]);
}

// ------------- xa[m][0..3] = x[m,:] @ [lora_q_a | lora_v_a] -------------
__global__ __launch_bounds__(256) void k_lora(const float* __restrict__ x,
                                              const float* __restrict__ qa,
                                              const float* __restrict__ va,
                                              float* __restrict__ xa) {
  int row = blockIdx.x * 4 + (threadIdx.x >> 6);
  int lane = threadIdx.x & 63;
  const float* xr = x + (size_t)row * D_;
  float a0 = 0, a1 = 0, a2 = 0, a3 = 0;
  for (int k = lane; k < D_; k += 64) {
    float xv = xr[k];
    a0 += xv * qa[2 * k];  a1 += xv * qa[2 * k + 1];
    a2 += xv * va[2 * k];  a3 += xv * va[2 * k + 1];
  }
#pragma unroll
  for (int off = 32; off; off >>= 1) {
    a0 += __shfl_down(a0, off, 64);
    a1 += __shfl_down(a1, off, 64);
    a2 += __shfl_down(a2, off, 64);
    a3 += __shfl_down(a3, off, 64);
  }
  if (lane == 0) {
    float* o = xa + (size_t)row * 4;
    o[0] = a0; o[1] = a1; o[2] = a2; o[3] = a3;
  }
}

// ---------------- partial add (split-K reduction) ----------------
__global__ __launch_bounds__(256) void k_add(const float* __restrict__ a,
                                             const float* __restrict__ b,
                                             float* __restrict__ o, int n4) {
  int i = blockIdx.x * 256 + threadIdx.x;
  if (i >= n4) return;
  float4 x = ((const float4*)a)[i], y = ((const float4*)b)[i];
  float4 r = {x.x + y.x, x.y + y.y, x.z + y.z, x.w + y.w};
  ((float4*)o)[i] = r;
}

// ==================== 256x256 8-phase bf16 GEMM ====================
// C[M x N] = A[M x K] * Bt[N x K]^T (+ rank-2 LoRA epilogue).
// 8 waves (2Mx4N), BK=64, 128KB LDS dbuf. Prefetch roles: A (L2-hot)
// 1-tile lookahead into nxt; B (HBM-hot) 2-tile lookahead into cur.
// Counted vmcnt(4); XOR swizzle via pre-swizzled global source.
// gridDim.z==2 -> split-K halves, z=0 writes C, z=1 writes Cb.
#define STAGE_A(HALF, KT, DBUF) do {                                         \
    const ushort* gp_ = A + (size_t)(m0 + (HALF) * 128 + w * 16 + srow) * Kz \
                          + kz0 + (KT) * 64 + scol;                          \
    char* lp_ = lds + (DBUF) * 65536 + (HALF) * 16384 + w * 2048;            \
    gload16(gp_, lp_);                                                       \
    gload16(gp_ + 8 * Kz, lp_ + 1024);                                       \
  } while (0)

#define STAGE_B(HALF, KT, DBUF) do {                                         \
    const ushort* gp_ = Bt + (size_t)(n0 + (HALF) * 128 + w * 16 + srow) * Kz\
                          + kz0 + (KT) * 64 + scol;                          \
    char* lp_ = lds + (DBUF) * 65536 + 32768 + (HALF) * 16384 + w * 2048;    \
    gload16(gp_, lp_);                                                       \
    gload16(gp_ + 8 * Kz, lp_ + 1024);                                       \
  } while (0)

#define LOAD_AF(QA, CUR) do {                                                \
    const char* ab_ = lds + (CUR) * 65536 + (QA) * 16384 + (wr * 64 + lr) * 128; \
    _Pragma("unroll") for (int fr = 0; fr < 4; fr++)                         \
    _Pragma("unroll") for (int ks = 0; ks < 2; ks++)                         \
      af[fr][ks] = *(const short8*)(ab_ + fr * 2048 + (((ks * 4 + g) * 16) ^ swz)); \
  } while (0)

#define LOAD_BF(QB, CUR, BF) do {                                            \
    const char* bb_ = lds + (CUR) * 65536 + 32768 + (QB) * 16384 + (wc * 32 + lr) * 128; \
    _Pragma("unroll") for (int fc = 0; fc < 2; fc++)                         \
    _Pragma("unroll") for (int ks = 0; ks < 2; ks++)                         \
      BF[fc][ks] = *(const short8*)(bb_ + fc * 2048 + (((ks * 4 + g) * 16) ^ swz)); \
  } while (0)

#define MFMA16(QA, QB, BF) do {                                              \
    __builtin_amdgcn_s_setprio(1);                                           \
    _Pragma("unroll") for (int fr = 0; fr < 4; fr++)                         \
    _Pragma("unroll") for (int fc = 0; fc < 2; fc++)                         \
    _Pragma("unroll") for (int ks = 0; ks < 2; ks++)                         \
      acc[(QA) * 4 + fr][(QB) * 2 + fc] = __builtin_amdgcn_mfma_f32_16x16x32_bf16( \
          af[fr][ks], BF[fc][ks], acc[(QA) * 4 + fr][(QB) * 2 + fc], 0, 0, 0);     \
    __builtin_amdgcn_s_setprio(0);                                           \
  } while (0)

#define GBAR __builtin_amdgcn_s_barrier()
#define LGKM0 asm volatile("s_waitcnt lgkmcnt(0)" ::: "memory")

__global__ __launch_bounds__(512, 2) void k_gemm8(const ushort* __restrict__ A,
                                                  const ushort* __restrict__ Bt,
                                                  float* __restrict__ C,
                                                  float* __restrict__ Cb,
                                                  int N, int K,
                                                  const float* __restrict__ xa,
                                                  const float* __restrict__ qb,
                                                  const float* __restrict__ vb) {
  __shared__ char lds[131072];
  // bijective XCD swizzle within a z-slice (nwg % 8 == 0 for all launches)
  const int nbx = gridDim.x;
  const int nwg = nbx * gridDim.y;
  const int flat = blockIdx.y * nbx + blockIdx.x;
  const int swz_id = (flat & 7) * (nwg >> 3) + (flat >> 3);
  const int m0 = (swz_id / nbx) * 256, n0 = (swz_id % nbx) * 256;
  // split-K
  const int kz0 = (gridDim.z == 2) ? (int)blockIdx.z * (K >> 1) : 0;
  const int NK = ((gridDim.z == 2) ? (K >> 1) : K) >> 6;
  float* __restrict__ Cout = blockIdx.z ? Cb : C;

  const int tid = threadIdx.x, lane = tid & 63, w = tid >> 6;
  const int wr = w >> 2, wc = w & 3;  // 2 x 4 waves
  const int lr = lane & 15, g = lane >> 4;
  const int swz = (lr & 7) * 16;
  const size_t Kz = (size_t)K;
  const int srow = lane >> 3;                           // 0..7
  const int scol = ((lane & 7) ^ (srow & 7)) * 8;       // pre-swizzled source col

  floatx4 acc[8][4] = {};
  short8 af[4][2], bf0[2][2], bf1[2][2];

  // prologue: tile 0 fully (A then B) + B halves of tile 1
  STAGE_A(0, 0, 0); STAGE_A(1, 0, 0); STAGE_B(0, 0, 0); STAGE_B(1, 0, 0);
  if (NK > 1) { STAGE_B(0, 1, 1); STAGE_B(1, 1, 1); }
  if (NK > 1) asm volatile("s_waitcnt vmcnt(4)" ::: "memory");
  else        asm volatile("s_waitcnt vmcnt(0)" ::: "memory");
  GBAR;

  for (int k = 0; k < NK; ++k) {
    const int cur = k & 1, nxt = cur ^ 1;
    // P0: quadrant (0,0); stage A0(k+1) -> nxt
    LOAD_AF(0, cur);
    LOAD_BF(0, cur, bf0);
    if (k + 1 < NK) STAGE_A(0, k + 1, nxt);
    GBAR; LGKM0; MFMA16(0, 0, bf0); GBAR;
    // P1: quadrant (0,1); stage A1(k+1) -> nxt
    LOAD_BF(1, cur, bf1);
    if (k + 1 < NK) STAGE_A(1, k + 1, nxt);
    GBAR; LGKM0; MFMA16(0, 1, bf1); GBAR;
    // P2: quadrant (1,1); stage B0(k+2) -> cur (B0 cur last read at P0)
    LOAD_AF(1, cur);
    if (k + 2 < NK) STAGE_B(0, k + 2, cur);
    GBAR; LGKM0; MFMA16(1, 1, bf1); GBAR;
    // P3: quadrant (1,0); stage B1(k+2) -> cur (B1 cur last read at P1)
    if (k + 2 < NK) STAGE_B(1, k + 2, cur);
    if (k < NK - 2) asm volatile("s_waitcnt vmcnt(4)" ::: "memory");
    else            asm volatile("s_waitcnt vmcnt(0)" ::: "memory");
    GBAR; LGKM0; MFMA16(1, 0, bf0); GBAR;
  }

  // epilogue: C write + optional rank-2 LoRA
#pragma unroll
  for (int qa = 0; qa < 2; qa++)
#pragma unroll
    for (int fr = 0; fr < 4; fr++) {
      const int mb = m0 + qa * 128 + wr * 64 + fr * 16 + g * 4;
#pragma unroll
      for (int qb_ = 0; qb_ < 2; qb_++)
#pragma unroll
        for (int fc = 0; fc < 2; fc++) {
          const int n = n0 + qb_ * 128 + wc * 32 + fc * 16 + lr;
#pragma unroll
          for (int r = 0; r < 4; r++) {
            const int m = mb + r;
            float c = acc[qa * 4 + fr][qb_ * 2 + fc][r];
            if (xa) {
              if (n < 4096)
                c += xa[(size_t)m * 4 + 0] * qb[n] +
                     xa[(size_t)m * 4 + 1] * qb[4096 + n];
              else if (n >= 5120)
                c += xa[(size_t)m * 4 + 2] * vb[n - 5120] +
                     xa[(size_t)m * 4 + 3] * vb[1024 + n - 5120];
            }
            Cout[(size_t)m * N + n] = c;
          }
        }
    }
}

// ---- RoPE (interleaved pairs) + repack to (b,h,s,d) bf16 for Q and K ----
__global__ __launch_bounds__(256) void k_rope(const float* __restrict__ xqkv,
                                              const float* __restrict__ fcos,
                                              const float* __restrict__ fsin,
                                              ushort* __restrict__ Qb,
                                              ushort* __restrict__ Kb) {
  const int s = blockIdx.x, b = blockIdx.y;
  const float* row = xqkv + (size_t)(b * S_ + s) * 6144;
#pragma unroll
  for (int it = 0; it < 8; it++) {  // Q: 32 heads * 64 pairs
    int p2 = it * 256 + threadIdx.x;
    int h = p2 >> 6, p = p2 & 63;
    float2 ab = *(const float2*)(row + h * 128 + 2 * p);
    float c = fcos[s * 64 + p], sn = fsin[s * 64 + p];
    uint32_t pk = (uint32_t)f2bf(ab.x * c - ab.y * sn) |
                  ((uint32_t)f2bf(ab.x * sn + ab.y * c) << 16);
    *(uint32_t*)(Qb + ((size_t)(b * H_ + h) * S_ + s) * HD_ + 2 * p) = pk;
  }
#pragma unroll
  for (int it = 0; it < 2; it++) {  // K: 8 heads * 64 pairs
    int p2 = it * 256 + threadIdx.x;
    int h = p2 >> 6, p = p2 & 63;
    float2 ab = *(const float2*)(row + 4096 + h * 128 + 2 * p);
    float c = fcos[s * 64 + p], sn = fsin[s * 64 + p];
    uint32_t pk = (uint32_t)f2bf(ab.x * c - ab.y * sn) |
                  ((uint32_t)f2bf(ab.x * sn + ab.y * c) << 16);
    *(uint32_t*)(Kb + ((size_t)(b * KVH_ + h) * S_ + s) * HD_ + 2 * p) = pk;
  }
}

// ==================== flash attention, LDS-staged K/V ====================
#define FSTAGE(T, DB) do {                                                   \
    _Pragma("unroll") for (int i_ = 0; i_ < 4; i_++) {                       \
      gload16(Kg + (size_t)((T) * 64 + i_ * 16 + k_srow) * HD_ + k_scol,     \
              fls + (DB) * 16384 + i_ * 4096 + w * 1024);                    \
      gload16(Vg + (size_t)(i_ * 32 + v_srow) * S_ + (T) * 64 + v_scol,      \
              fls + 32768 + (DB) * 16384 + i_ * 4096 + w * 1024);            \
    }                                                                        \
  } while (0)

__global__ __launch_bounds__(256, 2) void k_flash(const ushort* __restrict__ Qb,
                                                  const ushort* __restrict__ Kb,
                                                  const ushort* __restrict__ Vt,
                                                  ushort* __restrict__ attn) {
  __shared__ char fls[73728];  // K dbuf 32KB | V dbuf 32KB | P 8KB
  const int qblk = (gridDim.x - 1) - blockIdx.x;  // heavy blocks first
  const int h = blockIdx.y, b = blockIdx.z;
  const int kvh = h >> 2;
  const int tid = threadIdx.x, w = tid >> 6, lane = tid & 63;
  const int lr = lane & 15, g = lane >> 4;
  const int swz = (lr & 7) * 16;
  const int qr0 = qblk * 64 + w * 16;
  const ushort* Qrow = Qb + ((size_t)(b * H_ + h) * S_ + qr0 + lr) * HD_;
  short8 qf[4];
#pragma unroll
  for (int ks = 0; ks < 4; ks++) qf[ks] = *(const short8*)(Qrow + ks * 32 + g * 8);
  const ushort* Kg = Kb + (size_t)(b * KVH_ + kvh) * S_ * HD_;
  const ushort* Vg = Vt + (size_t)(b * KVH_ + kvh) * HD_ * S_;
  char* Pw = fls + 65536 + w * 2048;
  const int q7 = lr & 7;
  const int k_srow = tid >> 4;                          // 0..15
  const int k_scol = ((tid & 15) ^ (k_srow & 7)) * 8;   // pre-swizzled
  const int v_srow = tid >> 3;                          // 0..31
  const int v_scol = ((tid & 7) ^ (v_srow & 7)) * 8;

  float m_run = -1e30f, l_run = 0.f;
  floatx4 o[8] = {};
  const int nt = qblk + 1;

  FSTAGE(0, 0);
  asm volatile("s_waitcnt vmcnt(0)" ::: "memory");
  __builtin_amdgcn_s_barrier();

  for (int t = 0; t < nt; t++) {
    const int cur = t & 1;
    if (t + 1 < nt) FSTAGE(t + 1, cur ^ 1);
    const char* Kl = fls + cur * 16384;
    const char* Vl = fls + 32768 + cur * 16384;
    floatx4 s4[4] = {};
    __builtin_amdgcn_s_setprio(1);
#pragma unroll
    for (int mf = 0; mf < 4; mf++) {
      const char* Krow = Kl + (mf * 16 + lr) * 256;
#pragma unroll
      for (int ks = 0; ks < 4; ks++) {
        short8 kf = *(const short8*)(Krow + (((ks * 4 + g) * 16) ^ swz));
        s4[mf] = __builtin_amdgcn_mfma_f32_16x16x32_bf16(kf, qf[ks], s4[mf], 0, 0, 0);
      }
    }
    __builtin_amdgcn_s_setprio(0);
    const float scale = 0.088388347648318447f;  // 1/sqrt(128)
    float tm = -1e30f;
    if (t == nt - 1) {
#pragma unroll
      for (int mf = 0; mf < 4; mf++)
#pragma unroll
        for (int r = 0; r < 4; r++) {
          int kv = t * 64 + mf * 16 + g * 4 + r;
          float v = (kv > qr0 + lr) ? -1e30f : s4[mf][r] * scale;
          s4[mf][r] = v;
          tm = fmaxf(tm, v);
        }
    } else {
#pragma unroll
      for (int mf = 0; mf < 4; mf++)
#pragma unroll
        for (int r = 0; r < 4; r++) {
          float v = s4[mf][r] * scale;
          s4[mf][r] = v;
          tm = fmaxf(tm, v);
        }
    }
    tm = fmaxf(tm, __shfl_xor(tm, 16, 64));
    tm = fmaxf(tm, __shfl_xor(tm, 32, 64));
    float m_new = fmaxf(m_run, tm);
    float corr = __expf(m_run - m_new);
    float rs = 0.f;
#pragma unroll
    for (int mf = 0; mf < 4; mf++)
#pragma unroll
      for (int r = 0; r < 4; r++) {
        float p = __expf(s4[mf][r] - m_new);
        s4[mf][r] = p;
        rs += p;
      }
    rs += __shfl_xor(rs, 16, 64);
    rs += __shfl_xor(rs, 32, 64);
    l_run = l_run * corr + rs;
    m_run = m_new;
#pragma unroll
    for (int r = 0; r < 4; r++) {
      float cr = __shfl(corr, g * 4 + r, 64);
#pragma unroll
      for (int nf = 0; nf < 8; nf++) o[nf][r] *= cr;
    }
    // P^T -> LDS (per-wave buffer, XOR-swizzled)
#pragma unroll
    for (int mf = 0; mf < 4; mf++) {
      uint2 pv;
      pv.x = (uint32_t)f2bf(s4[mf][0]) | ((uint32_t)f2bf(s4[mf][1]) << 16);
      pv.y = (uint32_t)f2bf(s4[mf][2]) | ((uint32_t)f2bf(s4[mf][3]) << 16);
      *(uint2*)(Pw + lr * 128 + ((mf * 32 + g * 8) ^ (q7 << 4))) = pv;
    }
    // PV: O += P * V (V fragments from LDS, conflict-free)
    __builtin_amdgcn_s_setprio(1);
#pragma unroll
    for (int ks2 = 0; ks2 < 2; ks2++) {
      short8 pa = *(const short8*)(Pw + lr * 128 + ((ks2 * 64 + g * 16) ^ (q7 << 4)));
#pragma unroll
      for (int nf = 0; nf < 8; nf++) {
        short8 vf = *(const short8*)(Vl + (nf * 16 + lr) * 128 + (((ks2 * 4 + g) * 16) ^ swz));
        o[nf] = __builtin_amdgcn_mfma_f32_16x16x32_bf16(pa, vf, o[nf], 0, 0, 0);
      }
    }
    __builtin_amdgcn_s_setprio(0);
    asm volatile("s_waitcnt vmcnt(0)" ::: "memory");
    __builtin_amdgcn_s_barrier();
  }
  float linv = 1.0f / l_run;
  ushort* outp = attn + ((size_t)(b * S_) + qr0) * 4096 + h * 128;
#pragma unroll
  for (int r = 0; r < 4; r++) {
    float li = __shfl(linv, g * 4 + r, 64);
    ushort* orow = outp + (size_t)(g * 4 + r) * 4096;
#pragma unroll
    for (int nf = 0; nf < 8; nf++)
      orow[nf * 16 + lr] = f2bf(o[nf][r] * li);
  }
}

extern "C" void kernel_launch(void* const* d_in, const int* in_sizes, int n_in,
                              void* d_out, int out_size, void* d_ws, size_t ws_size,
                              hipStream_t stream) {
  (void)in_sizes; (void)n_in; (void)out_size; (void)ws_size;
  const float* x    = (const float*)d_in[0];
  const float* wq   = (const float*)d_in[1];
  const float* wk   = (const float*)d_in[2];
  const float* wv   = (const float*)d_in[3];
  const float* wo   = (const float*)d_in[4];
  const float* lqa  = (const float*)d_in[5];
  const float* lqb  = (const float*)d_in[6];
  const float* lva  = (const float*)d_in[7];
  const float* lvb  = (const float*)d_in[8];
  const float* fcos = (const float*)d_in[9];
  const float* fsin = (const float*)d_in[10];

  char* ws = (char*)d_ws;
  ushort* xb   = (ushort*)(ws + 0);           // x bf16              16,777,216 B
  ushort* wT   = (ushort*)(ws + 16777216);    // [wq|wk|wv]^T bf16   50,331,648 B (dead after QKV gemm)
  ushort* woT  = (ushort*)(ws + 67108864);    // wo^T bf16           33,554,432 B
  float*  xqkv = (float*) (ws + 100663296);   // 2048x6144 f32       50,331,648 B (dead after rope/V-tr)
  ushort* Qb   = (ushort*)(ws + 150994944);   // (b,h,s,d) bf16      16,777,216 B
  ushort* Kb   = (ushort*)(ws + 167772160);   // (b,kvh,s,d) bf16     4,194,304 B
  ushort* Vt   = (ushort*)(ws + 171966464);   // (b,kvh,d,s) bf16     4,194,304 B
  ushort* attn = (ushort*)(ws + 176160768);   // 2048x4096 bf16      16,777,216 B
  float*  xa   = (float*) (ws + 192937984);   // 2048x4 f32              32,768 B
  float*  p0   = (float*) (ws + 16777216);    // split-K partial 0 (reuses wT)
  float*  p1   = (float*) (ws + 100663296);   // split-K partial 1 (reuses xqkv)

  // 1) conversions / transposes
  k_cvt<<<4096, 256, 0, stream>>>(x, xb, 1048576);
  k_tr<<<dim3(128, 128), 256, 0, stream>>>(wq, wT, 4096, 4096);
  k_tr<<<dim3(32, 128), 256, 0, stream>>>(wk, wT + (size_t)4096 * 4096, 1024, 4096);
  k_tr<<<dim3(32, 128), 256, 0, stream>>>(wv, wT + (size_t)5120 * 4096, 1024, 4096);
  k_tr<<<dim3(128, 128), 256, 0, stream>>>(wo, woT, 4096, 4096);
  // 2) LoRA rank-2 projections
  k_lora<<<512, 256, 0, stream>>>(x, lqa, lva, xa);
  // 3) fused QKV GEMM + LoRA epilogue -> xqkv f32 (grid 24x8 = 192 wg)
  k_gemm8<<<dim3(24, 8, 1), 512, 0, stream>>>(xb, wT, xqkv, nullptr, 6144, 4096,
                                              xa, lqb, lvb);
  // 4) RoPE + repack Q,K ; V transpose (per batch)
  k_rope<<<dim3(1024, 2), 256, 0, stream>>>(xqkv, fcos, fsin, Qb, Kb);
  k_tr<<<dim3(32, 32), 256, 0, stream>>>(xqkv + 5120, Vt, 6144, 1024);
  k_tr<<<dim3(32, 32), 256, 0, stream>>>(xqkv + (size_t)1024 * 6144 + 5120, Vt + 1048576, 6144, 1024);
  // 5) flash attention -> attn bf16 (2048 x 4096)
  k_flash<<<dim3(16, 32, 2), 256, 0, stream>>>(Qb, Kb, Vt, attn);
  // 6) output projection, split-K x2 (256 wg, full GPU) -> partials -> d_out
  k_gemm8<<<dim3(16, 8, 2), 512, 0, stream>>>(attn, woT, p0, p1, 4096, 4096,
                                              nullptr, nullptr, nullptr);
  k_add<<<8192, 256, 0, stream>>>(p0, p1, (float*)d_out, 2097152);
}

// Round 4
// 372.323 us; speedup vs baseline: 1.8418x; 1.0308x over previous
//
#include <hip/hip_runtime.h>
#include <stdint.h>

#define B_ 2
#define S_ 1024
#define D_ 4096
#define H_ 32
#define KVH_ 8
#define HD_ 128

typedef short short8 __attribute__((ext_vector_type(8)));
typedef float floatx4 __attribute__((ext_vector_type(4)));

__device__ __forceinline__ ushort f2bf(float f) {
  union { float f; uint32_t u; } v; v.f = f;
  return (ushort)((v.u + 0x7FFFu + ((v.u >> 16) & 1u)) >> 16);
}

__device__ __forceinline__ void gload16(const void* g, void* l) {
  __builtin_amdgcn_global_load_lds((__attribute__((address_space(1))) void*)g,
                                   (__attribute__((address_space(3))) void*)l,
                                   16, 0, 0);
}

// ---------------- f32 -> bf16 convert (8 elems/thread) ----------------
__global__ __launch_bounds__(256) void k_cvt(const float* __restrict__ in,
                                             ushort* __restrict__ out, int n8) {
  int i = blockIdx.x * 256 + threadIdx.x;
  if (i >= n8) return;
  const float4* p = (const float4*)in + (size_t)i * 2;
  float4 a = p[0], b = p[1];
  ushort o8[8] = {f2bf(a.x), f2bf(a.y), f2bf(a.z), f2bf(a.w),
                  f2bf(b.x), f2bf(b.y), f2bf(b.z), f2bf(b.w)};
  *(uint4*)(out + (size_t)i * 8) = *(uint4*)o8;
}

// ---- f32 [R x C] -> bf16 transposed [C x R]; 64x64 tiles, vectorized ----
__global__ __launch_bounds__(256) void k_tr4(const float* __restrict__ in,
                                             ushort* __restrict__ out,
                                             int in_stride, int out_stride) {
  __shared__ float t[64][65];
  const int n0 = blockIdx.x * 64, k0 = blockIdx.y * 64;
  const int c4 = (threadIdx.x & 15) * 4, r = threadIdx.x >> 4;  // r 0..15
#pragma unroll
  for (int rr = 0; rr < 64; rr += 16) {
    float4 v = *(const float4*)&in[(size_t)(k0 + r + rr) * in_stride + n0 + c4];
    t[r + rr][c4] = v.x; t[r + rr][c4 + 1] = v.y;
    t[r + rr][c4 + 2] = v.z; t[r + rr][c4 + 3] = v.w;
  }
  __syncthreads();
#pragma unroll
  for (int rr = 0; rr < 64; rr += 16) {
    const int n = r + rr;
    ushort o4[4] = {f2bf(t[c4][n]), f2bf(t[c4 + 1][n]),
                    f2bf(t[c4 + 2][n]), f2bf(t[c4 + 3][n])};
    *(uint2*)&out[(size_t)(n0 + n) * out_stride + k0 + c4] = *(uint2*)o4;
  }
}

// ------------- xa[m][0..3] = x[m,:] @ [lora_q_a | lora_v_a] -------------
__global__ __launch_bounds__(256) void k_lora(const float* __restrict__ x,
                                              const float* __restrict__ qa,
                                              const float* __restrict__ va,
                                              float* __restrict__ xa) {
  int row = blockIdx.x * 4 + (threadIdx.x >> 6);
  int lane = threadIdx.x & 63;
  const float* xr = x + (size_t)row * D_;
  float a0 = 0, a1 = 0, a2 = 0, a3 = 0;
  for (int k = lane; k < D_; k += 64) {
    float xv = xr[k];
    a0 += xv * qa[2 * k];  a1 += xv * qa[2 * k + 1];
    a2 += xv * va[2 * k];  a3 += xv * va[2 * k + 1];
  }
#pragma unroll
  for (int off = 32; off; off >>= 1) {
    a0 += __shfl_down(a0, off, 64);
    a1 += __shfl_down(a1, off, 64);
    a2 += __shfl_down(a2, off, 64);
    a3 += __shfl_down(a3, off, 64);
  }
  if (lane == 0) {
    float* o = xa + (size_t)row * 4;
    o[0] = a0; o[1] = a1; o[2] = a2; o[3] = a3;
  }
}

// ---------------- partial add (split-K reduction) ----------------
__global__ __launch_bounds__(256) void k_add(const float* __restrict__ a,
                                             const float* __restrict__ b,
                                             float* __restrict__ o, int n4) {
  int i = blockIdx.x * 256 + threadIdx.x;
  if (i >= n4) return;
  float4 x = ((const float4*)a)[i], y = ((const float4*)b)[i];
  float4 r = {x.x + y.x, x.y + y.y, x.z + y.z, x.w + y.w};
  ((float4*)o)[i] = r;
}

// ==================== 256x256 8-phase/2-tile bf16 GEMM (m201 port) ========
// C[M x N] = A[M x K] * Bt[N x K]^T (+ rank-2 LoRA epilogue).
// 8 waves (2Mx4N), BK=64, 128KB LDS dbuf (1 K-tile per buffer).
// Each iteration: 2 K-tiles, 8 phases, 1 half-tile staged per phase,
// vmcnt(6) only at P4/P8 (3 half-tiles in flight). XOR swizzle via
// pre-swizzled global source. gridDim.z==2 -> split-K halves.
#define STAGE_A(HALF, KT) do {                                               \
    const ushort* gp_ = A + (size_t)(m0 + (HALF) * 128 + w * 16 + srow) * Kz \
                          + kz0 + (KT) * 64 + scol;                          \
    char* lp_ = lds + ((KT) & 1) * 65536 + (HALF) * 16384 + w * 2048;        \
    gload16(gp_, lp_);                                                       \
    gload16(gp_ + 8 * Kz, lp_ + 1024);                                       \
  } while (0)

#define STAGE_B(HALF, KT) do {                                               \
    const ushort* gp_ = Bt + (size_t)(n0 + (HALF) * 128 + w * 16 + srow) * Kz\
                          + kz0 + (KT) * 64 + scol;                          \
    char* lp_ = lds + ((KT) & 1) * 65536 + 32768 + (HALF) * 16384 + w * 2048;\
    gload16(gp_, lp_);                                                       \
    gload16(gp_ + 8 * Kz, lp_ + 1024);                                       \
  } while (0)

#define LOAD_AF(QA, BUF) do {                                                \
    const char* ab_ = lds + (BUF) * 65536 + (QA) * 16384 + (wr * 64 + lr) * 128; \
    _Pragma("unroll") for (int fr = 0; fr < 4; fr++)                         \
    _Pragma("unroll") for (int ks = 0; ks < 2; ks++)                         \
      af[fr][ks] = *(const short8*)(ab_ + fr * 2048 + (((ks * 4 + g) * 16) ^ swz)); \
  } while (0)

#define LOAD_BF(QB, BUF, BF) do {                                            \
    const char* bb_ = lds + (BUF) * 65536 + 32768 + (QB) * 16384 + (wc * 32 + lr) * 128; \
    _Pragma("unroll") for (int fc = 0; fc < 2; fc++)                         \
    _Pragma("unroll") for (int ks = 0; ks < 2; ks++)                         \
      BF[fc][ks] = *(const short8*)(bb_ + fc * 2048 + (((ks * 4 + g) * 16) ^ swz)); \
  } while (0)

#define MFMA16(QA, QB, BF) do {                                              \
    __builtin_amdgcn_s_setprio(1);                                           \
    _Pragma("unroll") for (int fr = 0; fr < 4; fr++)                         \
    _Pragma("unroll") for (int fc = 0; fc < 2; fc++)                         \
    _Pragma("unroll") for (int ks = 0; ks < 2; ks++)                         \
      acc[(QA) * 4 + fr][(QB) * 2 + fc] = __builtin_amdgcn_mfma_f32_16x16x32_bf16( \
          af[fr][ks], BF[fc][ks], acc[(QA) * 4 + fr][(QB) * 2 + fc], 0, 0, 0);     \
    __builtin_amdgcn_s_setprio(0);                                           \
  } while (0)

#define GBAR __builtin_amdgcn_s_barrier()
#define LGKM0 asm volatile("s_waitcnt lgkmcnt(0)" ::: "memory")
#define VMCNT6 asm volatile("s_waitcnt vmcnt(6)" ::: "memory")
#define VMCNT0 asm volatile("s_waitcnt vmcnt(0)" ::: "memory")

__global__ __launch_bounds__(512, 2) void k_gemm8(const ushort* __restrict__ A,
                                                  const ushort* __restrict__ Bt,
                                                  float* __restrict__ C,
                                                  float* __restrict__ Cb,
                                                  int N, int K,
                                                  const float* __restrict__ xa,
                                                  const float* __restrict__ qb,
                                                  const float* __restrict__ vb) {
  __shared__ char lds[131072];
  // bijective XCD swizzle within a z-slice (nwg % 8 == 0 for all launches)
  const int nbx = gridDim.x;
  const int nwg = nbx * gridDim.y;
  const int flat = blockIdx.y * nbx + blockIdx.x;
  const int swz_id = (flat & 7) * (nwg >> 3) + (flat >> 3);
  const int m0 = (swz_id / nbx) * 256, n0 = (swz_id % nbx) * 256;
  // split-K
  const int kz0 = (gridDim.z == 2) ? (int)blockIdx.z * (K >> 1) : 0;
  const int NK = ((gridDim.z == 2) ? (K >> 1) : K) >> 6;
  const int NJ = NK >> 1;  // 2 K-tiles per iteration
  float* __restrict__ Cout = blockIdx.z ? Cb : C;

  const int tid = threadIdx.x, lane = tid & 63, w = tid >> 6;
  const int wr = w >> 2, wc = w & 3;  // 2 x 4 waves
  const int lr = lane & 15, g = lane >> 4;
  const int swz = (lr & 7) * 16;
  const size_t Kz = (size_t)K;
  const int srow = lane >> 3;                           // 0..7
  const int scol = ((lane & 7) ^ (srow & 7)) * 8;       // pre-swizzled source col

  floatx4 acc[8][4] = {};
  short8 af[4][2], bf0[2][2], bf1[2][2];

  // prologue: 7 half-tiles staged (tile0 complete + A0,B0,A1 of tile1)
  STAGE_A(0, 0); STAGE_B(0, 0); STAGE_A(1, 0); STAGE_B(1, 0);
  STAGE_A(0, 1); STAGE_B(0, 1); STAGE_A(1, 1);
  VMCNT6;  // tile 0 landed; 3 halves of tile 1 in flight
  GBAR;

  for (int j = 0; j < NJ; ++j) {
    const int t0 = 2 * j, t1 = 2 * j + 1;
    const bool last = (j == NJ - 1);
    // P1: Q(A0,B0) of t0 [buf0]; stage B1(t1) -> buf1 completes
    LOAD_AF(0, 0);
    LOAD_BF(0, 0, bf0);
    STAGE_B(1, t1);
    GBAR; LGKM0; MFMA16(0, 0, bf0); GBAR;
    // P2: Q(A0,B1) t0; stage A0(t0+2)
    LOAD_BF(1, 0, bf1);
    if (t0 + 2 < NK) STAGE_A(0, t0 + 2);
    GBAR; LGKM0; MFMA16(0, 1, bf1); GBAR;
    // P3: Q(A1,B1) t0; stage B0(t0+2)
    LOAD_AF(1, 0);
    if (t0 + 2 < NK) STAGE_B(0, t0 + 2);
    GBAR; LGKM0; MFMA16(1, 1, bf1); GBAR;
    // P4: Q(A1,B0) t0; stage A1(t0+2); wait -> tile t1 complete
    if (t0 + 2 < NK) STAGE_A(1, t0 + 2);
    if (last) { VMCNT0; } else { VMCNT6; }
    GBAR; LGKM0; MFMA16(1, 0, bf0); GBAR;
    // P5: Q(A0,B0) of t1 [buf1]; stage B1(t0+2)
    LOAD_AF(0, 1);
    LOAD_BF(0, 1, bf0);
    if (t0 + 2 < NK) STAGE_B(1, t0 + 2);
    GBAR; LGKM0; MFMA16(0, 0, bf0); GBAR;
    // P6: Q(A0,B1) t1; stage A0(t1+2)
    LOAD_BF(1, 1, bf1);
    if (t1 + 2 < NK) STAGE_A(0, t1 + 2);
    GBAR; LGKM0; MFMA16(0, 1, bf1); GBAR;
    // P7: Q(A1,B1) t1; stage B0(t1+2)
    LOAD_AF(1, 1);
    if (t1 + 2 < NK) STAGE_B(0, t1 + 2);
    GBAR; LGKM0; MFMA16(1, 1, bf1); GBAR;
    // P8: Q(A1,B0) t1; stage A1(t1+2); wait -> tile t0+2 complete
    if (t1 + 2 < NK) STAGE_A(1, t1 + 2);
    if (last) { VMCNT0; } else { VMCNT6; }
    GBAR; LGKM0; MFMA16(1, 0, bf0); GBAR;
  }

  // epilogue: C write + optional rank-2 LoRA
#pragma unroll
  for (int qa = 0; qa < 2; qa++)
#pragma unroll
    for (int fr = 0; fr < 4; fr++) {
      const int mb = m0 + qa * 128 + wr * 64 + fr * 16 + g * 4;
#pragma unroll
      for (int qb_ = 0; qb_ < 2; qb_++)
#pragma unroll
        for (int fc = 0; fc < 2; fc++) {
          const int n = n0 + qb_ * 128 + wc * 32 + fc * 16 + lr;
#pragma unroll
          for (int r = 0; r < 4; r++) {
            const int m = mb + r;
            float c = acc[qa * 4 + fr][qb_ * 2 + fc][r];
            if (xa) {
              if (n < 4096)
                c += xa[(size_t)m * 4 + 0] * qb[n] +
                     xa[(size_t)m * 4 + 1] * qb[4096 + n];
              else if (n >= 5120)
                c += xa[(size_t)m * 4 + 2] * vb[n - 5120] +
                     xa[(size_t)m * 4 + 3] * vb[1024 + n - 5120];
            }
            Cout[(size_t)m * N + n] = c;
          }
        }
    }
}

// ---- RoPE (interleaved pairs) + repack to (b,h,s,d) bf16 for Q and K ----
__global__ __launch_bounds__(256) void k_rope(const float* __restrict__ xqkv,
                                              const float* __restrict__ fcos,
                                              const float* __restrict__ fsin,
                                              ushort* __restrict__ Qb,
                                              ushort* __restrict__ Kb) {
  const int s = blockIdx.x, b = blockIdx.y;
  const float* row = xqkv + (size_t)(b * S_ + s) * 6144;
#pragma unroll
  for (int it = 0; it < 8; it++) {  // Q: 32 heads * 64 pairs
    int p2 = it * 256 + threadIdx.x;
    int h = p2 >> 6, p = p2 & 63;
    float2 ab = *(const float2*)(row + h * 128 + 2 * p);
    float c = fcos[s * 64 + p], sn = fsin[s * 64 + p];
    uint32_t pk = (uint32_t)f2bf(ab.x * c - ab.y * sn) |
                  ((uint32_t)f2bf(ab.x * sn + ab.y * c) << 16);
    *(uint32_t*)(Qb + ((size_t)(b * H_ + h) * S_ + s) * HD_ + 2 * p) = pk;
  }
#pragma unroll
  for (int it = 0; it < 2; it++) {  // K: 8 heads * 64 pairs
    int p2 = it * 256 + threadIdx.x;
    int h = p2 >> 6, p = p2 & 63;
    float2 ab = *(const float2*)(row + 4096 + h * 128 + 2 * p);
    float c = fcos[s * 64 + p], sn = fsin[s * 64 + p];
    uint32_t pk = (uint32_t)f2bf(ab.x * c - ab.y * sn) |
                  ((uint32_t)f2bf(ab.x * sn + ab.y * c) << 16);
    *(uint32_t*)(Kb + ((size_t)(b * KVH_ + h) * S_ + s) * HD_ + 2 * p) = pk;
  }
}

// ==================== flash attention, LDS-staged K/V ====================
#define FSTAGE(T, DB) do {                                                   \
    _Pragma("unroll") for (int i_ = 0; i_ < 4; i_++) {                       \
      gload16(Kg + (size_t)((T) * 64 + i_ * 16 + k_srow) * HD_ + k_scol,     \
              fls + (DB) * 16384 + i_ * 4096 + w * 1024);                    \
      gload16(Vg + (size_t)(i_ * 32 + v_srow) * S_ + (T) * 64 + v_scol,      \
              fls + 32768 + (DB) * 16384 + i_ * 4096 + w * 1024);            \
    }                                                                        \
  } while (0)

__global__ __launch_bounds__(256, 2) void k_flash(const ushort* __restrict__ Qb,
                                                  const ushort* __restrict__ Kb,
                                                  const ushort* __restrict__ Vt,
                                                  ushort* __restrict__ attn) {
  __shared__ char fls[73728];  // K dbuf 32KB | V dbuf 32KB | P 8KB
  const int qblk = (gridDim.x - 1) - blockIdx.x;  // heavy blocks first
  const int h = blockIdx.y, b = blockIdx.z;
  const int kvh = h >> 2;
  const int tid = threadIdx.x, w = tid >> 6, lane = tid & 63;
  const int lr = lane & 15, g = lane >> 4;
  const int swz = (lr & 7) * 16;
  const int qr0 = qblk * 64 + w * 16;
  const ushort* Qrow = Qb + ((size_t)(b * H_ + h) * S_ + qr0 + lr) * HD_;
  short8 qf[4];
#pragma unroll
  for (int ks = 0; ks < 4; ks++) qf[ks] = *(const short8*)(Qrow + ks * 32 + g * 8);
  const ushort* Kg = Kb + (size_t)(b * KVH_ + kvh) * S_ * HD_;
  const ushort* Vg = Vt + (size_t)(b * KVH_ + kvh) * HD_ * S_;
  char* Pw = fls + 65536 + w * 2048;
  const int q7 = lr & 7;
  const int k_srow = tid >> 4;                          // 0..15
  const int k_scol = ((tid & 15) ^ (k_srow & 7)) * 8;   // pre-swizzled
  const int v_srow = tid >> 3;                          // 0..31
  const int v_scol = ((tid & 7) ^ (v_srow & 7)) * 8;

  float m_run = -1e30f, l_run = 0.f;
  floatx4 o[8] = {};
  const int nt = qblk + 1;

  FSTAGE(0, 0);
  asm volatile("s_waitcnt vmcnt(0)" ::: "memory");
  __builtin_amdgcn_s_barrier();

  for (int t = 0; t < nt; t++) {
    const int cur = t & 1;
    if (t + 1 < nt) FSTAGE(t + 1, cur ^ 1);
    const char* Kl = fls + cur * 16384;
    const char* Vl = fls + 32768 + cur * 16384;
    floatx4 s4[4] = {};
    __builtin_amdgcn_s_setprio(1);
#pragma unroll
    for (int mf = 0; mf < 4; mf++) {
      const char* Krow = Kl + (mf * 16 + lr) * 256;
#pragma unroll
      for (int ks = 0; ks < 4; ks++) {
        short8 kf = *(const short8*)(Krow + (((ks * 4 + g) * 16) ^ swz));
        s4[mf] = __builtin_amdgcn_mfma_f32_16x16x32_bf16(kf, qf[ks], s4[mf], 0, 0, 0);
      }
    }
    __builtin_amdgcn_s_setprio(0);
    const float scale = 0.088388347648318447f;  // 1/sqrt(128)
    float tm = -1e30f;
    if (t == nt - 1) {
#pragma unroll
      for (int mf = 0; mf < 4; mf++)
#pragma unroll
        for (int r = 0; r < 4; r++) {
          int kv = t * 64 + mf * 16 + g * 4 + r;
          float v = (kv > qr0 + lr) ? -1e30f : s4[mf][r] * scale;
          s4[mf][r] = v;
          tm = fmaxf(tm, v);
        }
    } else {
#pragma unroll
      for (int mf = 0; mf < 4; mf++)
#pragma unroll
        for (int r = 0; r < 4; r++) {
          float v = s4[mf][r] * scale;
          s4[mf][r] = v;
          tm = fmaxf(tm, v);
        }
    }
    tm = fmaxf(tm, __shfl_xor(tm, 16, 64));
    tm = fmaxf(tm, __shfl_xor(tm, 32, 64));
    float m_new = fmaxf(m_run, tm);
    float corr = __expf(m_run - m_new);
    float rs = 0.f;
#pragma unroll
    for (int mf = 0; mf < 4; mf++)
#pragma unroll
      for (int r = 0; r < 4; r++) {
        float p = __expf(s4[mf][r] - m_new);
        s4[mf][r] = p;
        rs += p;
      }
    rs += __shfl_xor(rs, 16, 64);
    rs += __shfl_xor(rs, 32, 64);
    l_run = l_run * corr + rs;
    m_run = m_new;
#pragma unroll
    for (int r = 0; r < 4; r++) {
      float cr = __shfl(corr, g * 4 + r, 64);
#pragma unroll
      for (int nf = 0; nf < 8; nf++) o[nf][r] *= cr;
    }
    // P^T -> LDS (per-wave buffer, XOR-swizzled)
#pragma unroll
    for (int mf = 0; mf < 4; mf++) {
      uint2 pv;
      pv.x = (uint32_t)f2bf(s4[mf][0]) | ((uint32_t)f2bf(s4[mf][1]) << 16);
      pv.y = (uint32_t)f2bf(s4[mf][2]) | ((uint32_t)f2bf(s4[mf][3]) << 16);
      *(uint2*)(Pw + lr * 128 + ((mf * 32 + g * 8) ^ (q7 << 4))) = pv;
    }
    // PV: O += P * V (V fragments from LDS, conflict-free)
    __builtin_amdgcn_s_setprio(1);
#pragma unroll
    for (int ks2 = 0; ks2 < 2; ks2++) {
      short8 pa = *(const short8*)(Pw + lr * 128 + ((ks2 * 64 + g * 16) ^ (q7 << 4)));
#pragma unroll
      for (int nf = 0; nf < 8; nf++) {
        short8 vf = *(const short8*)(Vl + (nf * 16 + lr) * 128 + (((ks2 * 4 + g) * 16) ^ swz));
        o[nf] = __builtin_amdgcn_mfma_f32_16x16x32_bf16(pa, vf, o[nf], 0, 0, 0);
      }
    }
    __builtin_amdgcn_s_setprio(0);
    asm volatile("s_waitcnt vmcnt(0)" ::: "memory");
    __builtin_amdgcn_s_barrier();
  }
  float linv = 1.0f / l_run;
  ushort* outp = attn + ((size_t)(b * S_) + qr0) * 4096 + h * 128;
#pragma unroll
  for (int r = 0; r < 4; r++) {
    float li = __shfl(linv, g * 4 + r, 64);
    ushort* orow = outp + (size_t)(g * 4 + r) * 4096;
#pragma unroll
    for (int nf = 0; nf < 8; nf++)
      orow[nf * 16 + lr] = f2bf(o[nf][r] * li);
  }
}

extern "C" void kernel_launch(void* const* d_in, const int* in_sizes, int n_in,
                              void* d_out, int out_size, void* d_ws, size_t ws_size,
                              hipStream_t stream) {
  (void)in_sizes; (void)n_in; (void)out_size; (void)ws_size;
  const float* x    = (const float*)d_in[0];
  const float* wq   = (const float*)d_in[1];
  const float* wk   = (const float*)d_in[2];
  const float* wv   = (const float*)d_in[3];
  const float* wo   = (const float*)d_in[4];
  const float* lqa  = (const float*)d_in[5];
  const float* lqb  = (const float*)d_in[6];
  const float* lva  = (const float*)d_in[7];
  const float* lvb  = (const float*)d_in[8];
  const float* fcos = (const float*)d_in[9];
  const float* fsin = (const float*)d_in[10];

  char* ws = (char*)d_ws;
  ushort* xb   = (ushort*)(ws + 0);           // x bf16              16,777,216 B
  ushort* wT   = (ushort*)(ws + 16777216);    // [wq|wk|wv]^T bf16   50,331,648 B (dead after QKV gemm)
  ushort* woT  = (ushort*)(ws + 67108864);    // wo^T bf16           33,554,432 B
  float*  xqkv = (float*) (ws + 100663296);   // 2048x6144 f32       50,331,648 B (dead after rope/V-tr)
  ushort* Qb   = (ushort*)(ws + 150994944);   // (b,h,s,d) bf16      16,777,216 B
  ushort* Kb   = (ushort*)(ws + 167772160);   // (b,kvh,s,d) bf16     4,194,304 B
  ushort* Vt   = (ushort*)(ws + 171966464);   // (b,kvh,d,s) bf16     4,194,304 B
  ushort* attn = (ushort*)(ws + 176160768);   // 2048x4096 bf16      16,777,216 B
  float*  xa   = (float*) (ws + 192937984);   // 2048x4 f32              32,768 B
  float*  p0   = (float*) (ws + 16777216);    // split-K partial 0 (reuses wT)
  float*  p1   = (float*) (ws + 100663296);   // split-K partial 1 (reuses xqkv)

  // 1) conversions / transposes (vectorized)
  k_cvt<<<4096, 256, 0, stream>>>(x, xb, 1048576);
  k_tr4<<<dim3(64, 64), 256, 0, stream>>>(wq, wT, 4096, 4096);
  k_tr4<<<dim3(16, 64), 256, 0, stream>>>(wk, wT + (size_t)4096 * 4096, 1024, 4096);
  k_tr4<<<dim3(16, 64), 256, 0, stream>>>(wv, wT + (size_t)5120 * 4096, 1024, 4096);
  k_tr4<<<dim3(64, 64), 256, 0, stream>>>(wo, woT, 4096, 4096);
  // 2) LoRA rank-2 projections
  k_lora<<<512, 256, 0, stream>>>(x, lqa, lva, xa);
  // 3) fused QKV GEMM + LoRA epilogue -> xqkv f32 (grid 24x8 = 192 wg)
  k_gemm8<<<dim3(24, 8, 1), 512, 0, stream>>>(xb, wT, xqkv, nullptr, 6144, 4096,
                                              xa, lqb, lvb);
  // 4) RoPE + repack Q,K ; V transpose (per batch)
  k_rope<<<dim3(1024, 2), 256, 0, stream>>>(xqkv, fcos, fsin, Qb, Kb);
  k_tr4<<<dim3(16, 16), 256, 0, stream>>>(xqkv + 5120, Vt, 6144, 1024);
  k_tr4<<<dim3(16, 16), 256, 0, stream>>>(xqkv + (size_t)1024 * 6144 + 5120, Vt + 1048576, 6144, 1024);
  // 5) flash attention -> attn bf16 (2048 x 4096)
  k_flash<<<dim3(16, 32, 2), 256, 0, stream>>>(Qb, Kb, Vt, attn);
  // 6) output projection, split-K x2 (256 wg, full GPU) -> partials -> d_out
  k_gemm8<<<dim3(16, 8, 2), 512, 0, stream>>>(attn, woT, p0, p1, 4096, 4096,
                                              nullptr, nullptr, nullptr);
  k_add<<<8192, 256, 0, stream>>>(p0, p1, (float*)d_out, 2097152);
}